// Round 18
// baseline (354.619 us; speedup 1.0000x reference)
//
#include <hip/hip_runtime.h>
#include <hip/hip_bf16.h>

#define NN 16384
#define DD 256
#define PANEL 64               // A rows per block (resident in LDS, 32KB)
#define JCOLS 128              // cols per j-tile
#define BK 32                  // k per step
#define NT 8                   // K-steps per j (NT*BK == DD)
#define NJ 32                  // j-tiles per block (4096 cols)
#define THREADS 128            // 2 waves (1m x 2n), wave = 64x64
#define A_BYTES (PANEL * DD * 2)   // 32768
#define SHIFT_C 64.0f
#define LOG2E 1.4426950408889634f

typedef __attribute__((ext_vector_type(4))) float f32x4;
typedef __attribute__((ext_vector_type(8))) short bf16x8;

#if __has_builtin(__builtin_amdgcn_exp2f)
#define EXP2F(x) __builtin_amdgcn_exp2f(x)
#else
#define EXP2F(x) exp2f(x)
#endif

__device__ __forceinline__ unsigned pkbf(float a, float b) {
  float2 t; t.x = a; t.y = b;
  __hip_bfloat162 h = __float22bfloat162_rn(t);
  union { __hip_bfloat162 h; unsigned u; } cv;
  cv.h = h;
  return cv.u;
}

__device__ __forceinline__ float rowsum16_dpp(float v) {
  union { float f; int i; } x, t;
  x.f = v;
  t.i = __builtin_amdgcn_update_dpp(0, x.i, 0x111, 0xf, 0xf, true); x.f += t.f;
  t.i = __builtin_amdgcn_update_dpp(0, x.i, 0x112, 0xf, 0xf, true); x.f += t.f;
  t.i = __builtin_amdgcn_update_dpp(0, x.i, 0x114, 0xf, 0xf, true); x.f += t.f;
  t.i = __builtin_amdgcn_update_dpp(0, x.i, 0x118, 0xf, 0xf, true); x.f += t.f;
  return x.f;
}

// ---------------- pre-convert f32 -> bf16 ----------------
__global__ __launch_bounds__(256) void cvt_kernel(
    const float* __restrict__ X, const float* __restrict__ Y,
    unsigned short* __restrict__ Xb, unsigned short* __restrict__ Yb) {
  const int groups_per_arr = NN * DD / 8;
  int g = blockIdx.x * 256 + threadIdx.x;
  const float* src;
  unsigned short* dst;
  if (g < groups_per_arr) { src = X; dst = Xb; }
  else { src = Y; dst = Yb; g -= groups_per_arr; }
  float4 a = ((const float4*)src)[(size_t)g * 2];
  float4 b = ((const float4*)src)[(size_t)g * 2 + 1];
  uint4 p = { pkbf(a.x, a.y), pkbf(a.z, a.w), pkbf(b.x, b.y), pkbf(b.z, b.w) };
  ((uint4*)dst)[g] = p;
}

// ---------------- main fused GEMM + softmax-stats ----------------
// Zero-barrier free-run, sized to the discovered constraints:
//  - 128-thread blocks => 192-VGPR cap (256-thr blocks clamp to 128: R12-R15)
//  - PANEL=64 A panel resident in 32KB LDS => 4 blocks/CU = 2 waves/SIMD
//    (R17's 1 wave/SIMD was the fat-wave failure mode)
//  - B streamed L2->registers, breg[2][4] double-buffered (32 arch VGPRs),
//    one-step read-ahead, statically indexed (full NT unroll)
//  - ONE __syncthreads total (after A fill); 256-step walk is barrier-free
__global__ __launch_bounds__(THREADS, 2) void clip_gemm(
    const unsigned short* __restrict__ Xb, const unsigned short* __restrict__ Yb,
    float* __restrict__ rowsum, float* __restrict__ colsum,
    float* __restrict__ diagsum) {
  __shared__ __align__(16) unsigned char sm[A_BYTES];  // 32KB static

  const int tid = threadIdx.x;
  const int bid = blockIdx.x;
  // 1024 blocks = 256 panels x 4 colgroups; single generation, 4 blocks/CU
  const int colgroup = bid & 3;
  const int panel = bid >> 2;                 // 0..255
  const int rowbase = panel * PANEL;
  const int colbase = colgroup * (NJ * JCOLS);

  const unsigned short* xb = Xb + (size_t)rowbase * DD;

  const int wn = tid >> 6, lane = tid & 63;   // wave wn owns cols [wn*64,+64) of each j-tile
  const int lm = lane & 15, lk = lane >> 4;

  // ---- A fill: 2048 slots of 16B ([64 rows][32 slots]); 16 per thread.
  // Physical slot s holds source subslot g = s ^ (row&7) (involution).
#pragma unroll
  for (int p = 0; p < 16; ++p) {
    const int s = p * 128 + tid;
    const int row = s >> 5;
    const int g = (s & 31) ^ (row & 7);
    __builtin_amdgcn_global_load_lds(
        (const __attribute__((address_space(1))) unsigned*)(xb + row * DD + g * 8),
        (__attribute__((address_space(3))) unsigned*)(sm + s * 16), 16, 0, 0);
  }

  // A read: row = m*16 + lm; physical slot = (t*4 + lk) ^ (lm&7)
#define RDA(m, t)                                                              \
  (*(const bf16x8*)(sm + ((m) * 16 + lm) * (DD * 2) +                          \
                    ((((t) * 4 + lk) ^ (lm & 7)) << 4)))

  // B fragment source: col = colbase + j*128 + wn*64 + nf*16 + lm; k = t*32 + lk*8.
  // Row-major Y -> 16 contiguous bytes per lane; wave reads 16 full 64B lines.
  const unsigned short* ybl = Yb + (size_t)(colbase + wn * 64 + lm) * DD + lk * 8;

#define LOADB(dst, jj, tt)                                                     \
  {                                                                            \
    _Pragma("unroll")                                                          \
    for (int nf = 0; nf < 4; ++nf)                                             \
      dst[nf] = *(const bf16x8*)(ybl + (size_t)((jj) * JCOLS + nf * 16) * DD + (tt) * BK); \
  }

  f32x4 acc[4][4] = {};
  float rowacc[4][4];
#pragma unroll
  for (int m = 0; m < 4; ++m)
#pragma unroll
    for (int r = 0; r < 4; ++r) rowacc[m][r] = 0.f;
  float dsum = 0.f;
  const float negC = -(SHIFT_C * LOG2E);

  bf16x8 breg[2][4];  // [parity][nf] — all indices static after unroll

  // prologue: load B(j=0, t=0) into parity 0 (independent of LDS)
  LOADB(breg[0], 0, 0);
  __syncthreads();  // the ONLY barrier: A resident for the whole kernel

  for (int j = 0; j < NJ; ++j) {
#pragma unroll
    for (int t = 0; t < NT; ++t) {
      // read-ahead: next step's B into the other parity (no barriers anywhere)
      if (t < NT - 1) { LOADB(breg[(t + 1) & 1], j, t + 1); }
      else if (j < NJ - 1) { LOADB(breg[0], j + 1, 0); }  // (t+1)&1 == 0 at t=7
#pragma unroll
      for (int m = 0; m < 4; ++m) {
        const bf16x8 a0 = RDA(m, t);
#pragma unroll
        for (int nf = 0; nf < 4; ++nf)
          acc[m][nf] = __builtin_amdgcn_mfma_f32_16x16x32_bf16(
              a0, breg[t & 1][nf], acc[m][nf], 0, 0, 0);
      }
    }

    // ---- per-j epilogue (runtime j-loop; waves fully independent) ----
    const int jc0 = colbase + j * JCOLS;
    float colacc[4] = {0.f, 0.f, 0.f, 0.f};
#pragma unroll
    for (int m = 0; m < 4; ++m)
#pragma unroll
      for (int nf = 0; nf < 4; ++nf)
#pragma unroll
        for (int r = 0; r < 4; ++r) {
          float e = EXP2F(__builtin_fmaf(acc[m][nf][r], LOG2E, negC));
          rowacc[m][r] += e;
          colacc[nf] += e;
        }
    if (jc0 < rowbase + PANEL && rowbase < jc0 + JCOLS) {  // diagonal overlap
#pragma unroll
      for (int m = 0; m < 4; ++m)
#pragma unroll
        for (int nf = 0; nf < 4; ++nf)
#pragma unroll
          for (int r = 0; r < 4; ++r) {
            const int gr = rowbase + m * 16 + lk * 4 + r;
            const int gc = jc0 + wn * 64 + nf * 16 + lm;
            if (gr == gc) dsum += acc[m][nf][r];
          }
    }
#pragma unroll
    for (int nf = 0; nf < 4; ++nf) {
      float v = colacc[nf];
      v += __shfl_xor(v, 16);
      v += __shfl_xor(v, 32);
      if (lk == 0)
        atomicAdd(&colsum[jc0 + wn * 64 + nf * 16 + lm], v);
    }
    const f32x4 z4 = {0.f, 0.f, 0.f, 0.f};
#pragma unroll
    for (int m = 0; m < 4; ++m)
#pragma unroll
      for (int nf = 0; nf < 4; ++nf) acc[m][nf] = z4;
  }
#undef LOADB
#undef RDA

  // ---- block-end: diagonal + row sums ----
  {
    float d = dsum;
    d += __shfl_xor(d, 1);
    d += __shfl_xor(d, 2);
    d += __shfl_xor(d, 4);
    d += __shfl_xor(d, 8);
    d += __shfl_xor(d, 16);
    d += __shfl_xor(d, 32);
    if (lane == 0 && d != 0.f) atomicAdd(diagsum, d);
  }
#pragma unroll
  for (int m = 0; m < 4; ++m)
#pragma unroll
    for (int r = 0; r < 4; ++r) {
      float v = rowsum16_dpp(rowacc[m][r]);
      if (lm == 15)
        atomicAdd(&rowsum[rowbase + m * 16 + lk * 4 + r], v);
    }
}

// ---------------- fallback (reg-staging, no ws bf16 buffers) ----------------
__global__ __launch_bounds__(256) void clip_main_fb(
    const float* __restrict__ X, const float* __restrict__ Y,
    float* __restrict__ rowsum, float* __restrict__ colsum,
    float* __restrict__ diagsum) {
  __shared__ __align__(16) unsigned char smem[2 * 128 * 64 * 2];
  unsigned char* smA = smem;
  unsigned char* smB = smem + 128 * 64 * 2;

  const int tid = threadIdx.x;
  const int bid = blockIdx.x;
  const int swz = (bid & 7) * 2048 + (bid >> 3);
  const int brow = swz >> 7;
  const int bcol = swz & 127;

  const float* xb = X + (size_t)brow * 128 * DD;
  const float* yb = Y + (size_t)bcol * 128 * DD;

  const int wid = tid >> 6, lane = tid & 63;
  const int wm = wid >> 1, wn = wid & 1;
  const int lm = lane & 15, lk = lane >> 4;

  f32x4 acc[4][4] = {};

  for (int ks = 0; ks < 4; ++ks) {
    const int kbase = ks * 64;
    if (ks) __syncthreads();
#pragma unroll
    for (int i = 0; i < 4; ++i) {
      const int c = tid + i * 256;
      const int row = c >> 3, slot = c & 7;
      const int boff = row * 128 + ((slot << 4) ^ ((row & 7) << 4));
      const float* ga = xb + row * DD + kbase + (slot << 3);
      float4 a0 = *(const float4*)ga;
      float4 a1 = *(const float4*)(ga + 4);
      uint4 pa = { pkbf(a0.x, a0.y), pkbf(a0.z, a0.w),
                   pkbf(a1.x, a1.y), pkbf(a1.z, a1.w) };
      *(uint4*)(smA + boff) = pa;
      const float* gb = yb + row * DD + kbase + (slot << 3);
      float4 b0 = *(const float4*)gb;
      float4 b1 = *(const float4*)(gb + 4);
      uint4 pb = { pkbf(b0.x, b0.y), pkbf(b0.z, b0.w),
                   pkbf(b1.x, b1.y), pkbf(b1.z, b1.w) };
      *(uint4*)(smB + boff) = pb;
    }
    __syncthreads();

#pragma unroll
    for (int kk = 0; kk < 2; ++kk) {
      const int kboff = kk * 64 + lk * 16;
      bf16x8 a[4], b[4];
#pragma unroll
      for (int m = 0; m < 4; ++m) {
        const int row = wm * 64 + m * 16 + lm;
        a[m] = *(const bf16x8*)(smA + row * 128 + (kboff ^ ((row & 7) << 4)));
      }
#pragma unroll
      for (int n = 0; n < 4; ++n) {
        const int row = wn * 64 + n * 16 + lm;
        b[n] = *(const bf16x8*)(smB + row * 128 + (kboff ^ ((row & 7) << 4)));
      }
#pragma unroll
      for (int m = 0; m < 4; ++m)
#pragma unroll
        for (int n = 0; n < 4; ++n)
          acc[m][n] = __builtin_amdgcn_mfma_f32_16x16x32_bf16(a[m], b[n], acc[m][n], 0, 0, 0);
    }
  }

  float rowacc[4][4];
  float colacc[4];
#pragma unroll
  for (int m = 0; m < 4; ++m)
#pragma unroll
    for (int r = 0; r < 4; ++r) rowacc[m][r] = 0.f;
#pragma unroll
  for (int n = 0; n < 4; ++n) colacc[n] = 0.f;

  const float negC = -(SHIFT_C * LOG2E);
#pragma unroll
  for (int m = 0; m < 4; ++m)
#pragma unroll
    for (int n = 0; n < 4; ++n)
#pragma unroll
      for (int r = 0; r < 4; ++r) {
        float e = EXP2F(__builtin_fmaf(acc[m][n][r], LOG2E, negC));
        rowacc[m][r] += e;
        colacc[n] += e;
      }

  if (brow == bcol && wm == wn) {
    float dsum = 0.f;
#pragma unroll
    for (int m = 0; m < 4; ++m)
#pragma unroll
      for (int n = 0; n < 4; ++n)
#pragma unroll
        for (int r = 0; r < 4; ++r) {
          const int rr = m * 16 + lk * 4 + r;
          const int cc = n * 16 + lm;
          if (rr == cc) dsum += acc[m][n][r];
        }
    dsum += __shfl_xor(dsum, 1);
    dsum += __shfl_xor(dsum, 2);
    dsum += __shfl_xor(dsum, 4);
    dsum += __shfl_xor(dsum, 8);
    dsum += __shfl_xor(dsum, 16);
    dsum += __shfl_xor(dsum, 32);
    if (lane == 0) atomicAdd(diagsum, dsum);
  }

#pragma unroll
  for (int m = 0; m < 4; ++m)
#pragma unroll
    for (int r = 0; r < 4; ++r) {
      float v = rowsum16_dpp(rowacc[m][r]);
      if (lm == 15)
        atomicAdd(&rowsum[brow * 128 + wm * 64 + m * 16 + lk * 4 + r], v);
    }
#pragma unroll
  for (int n = 0; n < 4; ++n) {
    float v = colacc[n];
    v += __shfl_xor(v, 16);
    v += __shfl_xor(v, 32);
    if (lk == 0)
      atomicAdd(&colsum[bcol * 128 + wn * 64 + n * 16 + lm], v);
  }
}

// ---------------- final reduction: parallel stats + tiny finisher ----------------
__global__ __launch_bounds__(256) void clip_stats(
    const float* __restrict__ rowsum, const float* __restrict__ colsum,
    float* __restrict__ partial) {
  __shared__ float sdata[4];
  const int i = blockIdx.x * 256 + threadIdx.x;
  float s = logf(rowsum[i]) + logf(colsum[i]);
  s += __shfl_xor(s, 1);
  s += __shfl_xor(s, 2);
  s += __shfl_xor(s, 4);
  s += __shfl_xor(s, 8);
  s += __shfl_xor(s, 16);
  s += __shfl_xor(s, 32);
  const int lane = threadIdx.x & 63, wv = threadIdx.x >> 6;
  if (lane == 0) sdata[wv] = s;
  __syncthreads();
  if (threadIdx.x == 0)
    atomicAdd(partial, sdata[0] + sdata[1] + sdata[2] + sdata[3]);
}

__global__ void clip_out(const float* __restrict__ partial,
                         const float* __restrict__ diagsum,
                         float* __restrict__ out) {
  if (threadIdx.x == 0)
    out[0] = (float)((double)SHIFT_C + (double)partial[0] * 0.5 / (double)NN
                     - (double)diagsum[0] / (double)NN);
}

extern "C" void kernel_launch(void* const* d_in, const int* in_sizes, int n_in,
                              void* d_out, int out_size, void* d_ws, size_t ws_size,
                              hipStream_t stream) {
  const float* X = (const float*)d_in[0];
  const float* Y = (const float*)d_in[1];

  const size_t bf16_bytes = (size_t)2 * NN * DD * sizeof(unsigned short);  // 16 MB
  const size_t stats_bytes = (size_t)(2 * NN + 2) * sizeof(float);

  if (ws_size >= bf16_bytes + stats_bytes) {
    unsigned short* Xb = (unsigned short*)d_ws;
    unsigned short* Yb = Xb + (size_t)NN * DD;
    float* rowsum = (float*)((unsigned char*)d_ws + bf16_bytes);
    float* colsum = rowsum + NN;
    float* diagsum = colsum + NN;
    float* partial = diagsum + 1;

    hipMemsetAsync(rowsum, 0, stats_bytes, stream);
    cvt_kernel<<<dim3(2 * NN * DD / 8 / 256), dim3(256), 0, stream>>>(X, Y, Xb, Yb);
    clip_gemm<<<dim3((NN / PANEL) * 4), dim3(THREADS), 0, stream>>>(
        Xb, Yb, rowsum, colsum, diagsum);
    clip_stats<<<dim3(NN / 256), dim3(256), 0, stream>>>(rowsum, colsum, partial);
    clip_out<<<dim3(1), dim3(64), 0, stream>>>(partial, diagsum, (float*)d_out);
  } else {
    float* rowsum = (float*)d_ws;
    float* colsum = rowsum + NN;
    float* diagsum = colsum + NN;
    float* partial = diagsum + 1;
    hipMemsetAsync(d_ws, 0, stats_bytes, stream);
    clip_main_fb<<<dim3((NN / 128) * (NN / 128)), dim3(256), 0, stream>>>(
        X, Y, rowsum, colsum, diagsum);
    clip_stats<<<dim3(NN / 256), dim3(256), 0, stream>>>(rowsum, colsum, partial);
    clip_out<<<dim3(1), dim3(64), 0, stream>>>(partial, diagsum, (float*)d_out);
  }
}

// Round 20
// 214.137 us; speedup vs baseline: 1.6560x; 1.6560x over previous
//
#include <hip/hip_runtime.h>
#include <hip/hip_bf16.h>

#define NN 16384
#define DD 256
#define PANEL 128              // A rows per block (resident in LDS, 64KB)
#define JCOLS 128              // cols per j-tile
#define BK 32                  // k per step
#define NT 8                   // K-steps per j (NT*BK == DD)
#define NJ 16                  // j-tiles per block (2048 cols)
#define THREADS 256            // 4 waves: 2m x 2n, wave = 64x64
#define A_BYTES (PANEL * DD * 2)   // 65536
#define B_BYTES (JCOLS * BK * 2)   // 8192
#define SHIFT_C 64.0f
#define LOG2E 1.4426950408889634f

typedef __attribute__((ext_vector_type(4))) float f32x4;
typedef __attribute__((ext_vector_type(8))) short bf16x8;

#if __has_builtin(__builtin_amdgcn_exp2f)
#define EXP2F(x) __builtin_amdgcn_exp2f(x)
#else
#define EXP2F(x) exp2f(x)
#endif

__device__ __forceinline__ unsigned pkbf(float a, float b) {
  float2 t; t.x = a; t.y = b;
  __hip_bfloat162 h = __float22bfloat162_rn(t);
  union { __hip_bfloat162 h; unsigned u; } cv;
  cv.h = h;
  return cv.u;
}

__device__ __forceinline__ float rowsum16_dpp(float v) {
  union { float f; int i; } x, t;
  x.f = v;
  t.i = __builtin_amdgcn_update_dpp(0, x.i, 0x111, 0xf, 0xf, true); x.f += t.f;
  t.i = __builtin_amdgcn_update_dpp(0, x.i, 0x112, 0xf, 0xf, true); x.f += t.f;
  t.i = __builtin_amdgcn_update_dpp(0, x.i, 0x114, 0xf, 0xf, true); x.f += t.f;
  t.i = __builtin_amdgcn_update_dpp(0, x.i, 0x118, 0xf, 0xf, true); x.f += t.f;
  return x.f;
}

// ---------------- pre-convert f32 -> bf16 ----------------
__global__ __launch_bounds__(256) void cvt_kernel(
    const float* __restrict__ X, const float* __restrict__ Y,
    unsigned short* __restrict__ Xb, unsigned short* __restrict__ Yb) {
  const int groups_per_arr = NN * DD / 8;
  int g = blockIdx.x * 256 + threadIdx.x;
  const float* src;
  unsigned short* dst;
  if (g < groups_per_arr) { src = X; dst = Xb; }
  else { src = Y; dst = Yb; g -= groups_per_arr; }
  float4 a = ((const float4*)src)[(size_t)g * 2];
  float4 b = ((const float4*)src)[(size_t)g * 2 + 1];
  uint4 p = { pkbf(a.x, a.y), pkbf(a.z, a.w), pkbf(b.x, b.y), pkbf(b.z, b.w) };
  ((uint4*)dst)[g] = p;
}

// ---------------- main fused GEMM + softmax-stats ----------------
// EXACT R16 structure (verified: 194us total, VGPR 88, no spill, absmax 0)
// + ONE addition: s_setprio(1) around the MFMA cluster (T5). With 2
// independent co-resident blocks/CU whose barriers are mutually unaligned,
// waves on a SIMD are at DIFFERENT phases (stage/barrier vs MFMA) — the
// regime where setprio pays (guide m191); null on lockstep GEMM (m190).
// R19's counted-vmcnt FAILED: vmcnt is per-wave, so vmcnt-after-barrier
// doesn't cover other waves' stage loads; correct T4 needs depth-2 = 3 B
// buffers = 88KB LDS, which kills 2-block co-residency. T4 arc closed.
__global__ __launch_bounds__(THREADS, 2) void clip_gemm(
    const unsigned short* __restrict__ Xb, const unsigned short* __restrict__ Yb,
    float* __restrict__ rowsum, float* __restrict__ colsum,
    float* __restrict__ diagsum) {
  __shared__ __align__(16) unsigned char sm[A_BYTES + 2 * B_BYTES];  // 80KB

  const int tid = threadIdx.x;
  const int bid = blockIdx.x;
  // 1024 blocks = 8 colgroups (XCD-pinned: 1MB Y slice per XCD L2) x 128 panels
  const int colgroup = bid & 7;
  const int panel = bid >> 3;                 // 0..127
  const int rowbase = panel * PANEL;
  const int colbase = colgroup * (NJ * JCOLS);

  const unsigned short* xb = Xb + (size_t)rowbase * DD;
  const unsigned short* ybg = Yb + (size_t)colbase * DD;

  const int wid = tid >> 6, lane = tid & 63;
  const int wm = wid >> 1, wn = wid & 1;   // wave = rows [wm*64,+64) x cols [wn*64,+64)
  const int lm = lane & 15, lk = lane >> 4;

  // ---- A fill: 4096 slots of 16B ([128 rows][32 slots]); 16 per thread.
  // Physical slot s holds logical subslot g = s ^ (row&7) (involution).
#pragma unroll
  for (int p = 0; p < 16; ++p) {
    const int s = p * 256 + tid;
    const int row = s >> 5;
    const int g = (s & 31) ^ (row & 7);
    __builtin_amdgcn_global_load_lds(
        (const __attribute__((address_space(1))) unsigned*)(xb + row * DD + g * 8),
        (__attribute__((address_space(3))) unsigned*)(sm + s * 16), 16, 0, 0);
  }

  // ---- B staging offsets: 512 slots of 16B ([128 cols][4 slots]); 2/thread.
  // Physical slot holds logical subslot g = (s&3) ^ (col&3) (involution).
  int bsrc[2], bdst[2];
#pragma unroll
  for (int p = 0; p < 2; ++p) {
    const int s = p * 256 + tid;
    const int col = s >> 2;
    const int g = (s & 3) ^ (col & 3);
    bsrc[p] = col * DD + g * 8;                 // + jn*JCOLS*DD + tn*BK
    bdst[p] = A_BYTES + s * 16;                 // + buf*B_BYTES
  }

#define GLOADB(jn, tn, buf)                                                    \
  {                                                                            \
    _Pragma("unroll")                                                          \
    for (int p = 0; p < 2; ++p)                                                \
      __builtin_amdgcn_global_load_lds(                                        \
          (const __attribute__((address_space(1))) unsigned*)(ybg + (size_t)(jn) * (JCOLS * DD) + bsrc[p] + (tn) * BK), \
          (__attribute__((address_space(3))) unsigned*)(sm + (buf) * B_BYTES + bdst[p]), \
          16, 0, 0);                                                           \
  }

  // A read: row = wm*64 + m*16 + lm; physical slot = (t*4 + lk) ^ (lm&7)
#define RDA(m, t)                                                              \
  (*(const bf16x8*)(sm + (wm * 64 + (m) * 16 + lm) * (DD * 2) +                \
                    ((((t) * 4 + lk) ^ (lm & 7)) << 4)))
  // B read: col = wn*64 + nf*16 + lm; physical slot = lk ^ (lm&3)
#define RDB(nf, buf)                                                           \
  (*(const bf16x8*)(sm + A_BYTES + (buf) * B_BYTES +                           \
                    (wn * 64 + (nf) * 16 + lm) * (BK * 2) +                    \
                    ((lk ^ (lm & 3)) << 4)))

  f32x4 acc[4][4] = {};
  float rowacc[4][4];
#pragma unroll
  for (int m = 0; m < 4; ++m)
#pragma unroll
    for (int r = 0; r < 4; ++r) rowacc[m][r] = 0.f;
  float dsum = 0.f;
  const float negC = -(SHIFT_C * LOG2E);

  // prologue: stage B(j=0, t=0) -> buf 0 (drained by the first barrier)
  GLOADB(0, 0, 0);

  for (int j = 0; j < NJ; ++j) {
#pragma unroll
    for (int t = 0; t < NT; ++t) {
      __syncthreads();  // drain: A fill (first time) + B stage of this step
      // stage next step into the other buffer (one-step runway)
      if (t < NT - 1) { GLOADB(j, t + 1, (t + 1) & 1); }
      else if (j < NJ - 1) { GLOADB(j + 1, 0, 0); }   // (t+1)&1 == 0 at t=7
      const int buf = t & 1;
      bf16x8 b0[4];
#pragma unroll
      for (int nf = 0; nf < 4; ++nf) b0[nf] = RDB(nf, buf);
      __builtin_amdgcn_s_setprio(1);
#pragma unroll
      for (int m = 0; m < 4; ++m) {
        const bf16x8 a0 = RDA(m, t);
#pragma unroll
        for (int nf = 0; nf < 4; ++nf)
          acc[m][nf] = __builtin_amdgcn_mfma_f32_16x16x32_bf16(a0, b0[nf], acc[m][nf], 0, 0, 0);
      }
      __builtin_amdgcn_s_setprio(0);
    }

    // ---- per-j epilogue (runtime j-loop; overlaps next j's first stage) ----
    const int jc0 = colbase + j * JCOLS;
    float colacc[4] = {0.f, 0.f, 0.f, 0.f};
#pragma unroll
    for (int m = 0; m < 4; ++m)
#pragma unroll
      for (int nf = 0; nf < 4; ++nf)
#pragma unroll
        for (int r = 0; r < 4; ++r) {
          float e = EXP2F(__builtin_fmaf(acc[m][nf][r], LOG2E, negC));
          rowacc[m][r] += e;
          colacc[nf] += e;
        }
    if (jc0 == rowbase) {  // square 128-tiles: diagonal overlap iff equal
#pragma unroll
      for (int m = 0; m < 4; ++m)
#pragma unroll
        for (int nf = 0; nf < 4; ++nf)
#pragma unroll
          for (int r = 0; r < 4; ++r) {
            const int rr = wm * 64 + m * 16 + lk * 4 + r;
            const int cc = wn * 64 + nf * 16 + lm;
            if (rr == cc) dsum += acc[m][nf][r];
          }
    }
#pragma unroll
    for (int nf = 0; nf < 4; ++nf) {
      float v = colacc[nf];
      v += __shfl_xor(v, 16);
      v += __shfl_xor(v, 32);
      if (lk == 0)
        atomicAdd(&colsum[jc0 + wn * 64 + nf * 16 + lm], v);
    }
    const f32x4 z4 = {0.f, 0.f, 0.f, 0.f};
#pragma unroll
    for (int m = 0; m < 4; ++m)
#pragma unroll
      for (int nf = 0; nf < 4; ++nf) acc[m][nf] = z4;
  }
#undef GLOADB
#undef RDA
#undef RDB

  // ---- block-end: diagonal + row sums ----
  {
    float d = dsum;
    d += __shfl_xor(d, 1);
    d += __shfl_xor(d, 2);
    d += __shfl_xor(d, 4);
    d += __shfl_xor(d, 8);
    d += __shfl_xor(d, 16);
    d += __shfl_xor(d, 32);
    if (lane == 0 && d != 0.f) atomicAdd(diagsum, d);
  }
#pragma unroll
  for (int m = 0; m < 4; ++m)
#pragma unroll
    for (int r = 0; r < 4; ++r) {
      float v = rowsum16_dpp(rowacc[m][r]);
      if (lm == 15)
        atomicAdd(&rowsum[rowbase + wm * 64 + m * 16 + lk * 4 + r], v);
    }
}

// ---------------- fallback (reg-staging, no ws bf16 buffers) ----------------
__global__ __launch_bounds__(256) void clip_main_fb(
    const float* __restrict__ X, const float* __restrict__ Y,
    float* __restrict__ rowsum, float* __restrict__ colsum,
    float* __restrict__ diagsum) {
  __shared__ __align__(16) unsigned char smem[2 * 128 * 64 * 2];
  unsigned char* smA = smem;
  unsigned char* smB = smem + 128 * 64 * 2;

  const int tid = threadIdx.x;
  const int bid = blockIdx.x;
  const int swz = (bid & 7) * 2048 + (bid >> 3);
  const int brow = swz >> 7;
  const int bcol = swz & 127;

  const float* xb = X + (size_t)brow * 128 * DD;
  const float* yb = Y + (size_t)bcol * 128 * DD;

  const int wid = tid >> 6, lane = tid & 63;
  const int wm = wid >> 1, wn = wid & 1;
  const int lm = lane & 15, lk = lane >> 4;

  f32x4 acc[4][4] = {};

  for (int ks = 0; ks < 4; ++ks) {
    const int kbase = ks * 64;
    if (ks) __syncthreads();
#pragma unroll
    for (int i = 0; i < 4; ++i) {
      const int c = tid + i * 256;
      const int row = c >> 3, slot = c & 7;
      const int boff = row * 128 + ((slot << 4) ^ ((row & 7) << 4));
      const float* ga = xb + row * DD + kbase + (slot << 3);
      float4 a0 = *(const float4*)ga;
      float4 a1 = *(const float4*)(ga + 4);
      uint4 pa = { pkbf(a0.x, a0.y), pkbf(a0.z, a0.w),
                   pkbf(a1.x, a1.y), pkbf(a1.z, a1.w) };
      *(uint4*)(smA + boff) = pa;
      const float* gb = yb + row * DD + kbase + (slot << 3);
      float4 b0 = *(const float4*)gb;
      float4 b1 = *(const float4*)(gb + 4);
      uint4 pb = { pkbf(b0.x, b0.y), pkbf(b0.z, b0.w),
                   pkbf(b1.x, b1.y), pkbf(b1.z, b1.w) };
      *(uint4*)(smB + boff) = pb;
    }
    __syncthreads();

#pragma unroll
    for (int kk = 0; kk < 2; ++kk) {
      const int kboff = kk * 64 + lk * 16;
      bf16x8 a[4], b[4];
#pragma unroll
      for (int m = 0; m < 4; ++m) {
        const int row = wm * 64 + m * 16 + lm;
        a[m] = *(const bf16x8*)(smA + row * 128 + (kboff ^ ((row & 7) << 4)));
      }
#pragma unroll
      for (int n = 0; n < 4; ++n) {
        const int row = wn * 64 + n * 16 + lm;
        b[n] = *(const bf16x8*)(smB + row * 128 + (kboff ^ ((row & 7) << 4)));
      }
#pragma unroll
      for (int m = 0; m < 4; ++m)
#pragma unroll
        for (int n = 0; n < 4; ++n)
          acc[m][n] = __builtin_amdgcn_mfma_f32_16x16x32_bf16(a[m], b[n], acc[m][n], 0, 0, 0);
    }
  }

  float rowacc[4][4];
  float colacc[4];
#pragma unroll
  for (int m = 0; m < 4; ++m)
#pragma unroll
    for (int r = 0; r < 4; ++r) rowacc[m][r] = 0.f;
#pragma unroll
  for (int n = 0; n < 4; ++n) colacc[n] = 0.f;

  const float negC = -(SHIFT_C * LOG2E);
#pragma unroll
  for (int m = 0; m < 4; ++m)
#pragma unroll
    for (int n = 0; n < 4; ++n)
#pragma unroll
      for (int r = 0; r < 4; ++r) {
        float e = EXP2F(__builtin_fmaf(acc[m][n][r], LOG2E, negC));
        rowacc[m][r] += e;
        colacc[n] += e;
      }

  if (brow == bcol && wm == wn) {
    float dsum = 0.f;
#pragma unroll
    for (int m = 0; m < 4; ++m)
#pragma unroll
      for (int n = 0; n < 4; ++n)
#pragma unroll
        for (int r = 0; r < 4; ++r) {
          const int rr = m * 16 + lk * 4 + r;
          const int cc = n * 16 + lm;
          if (rr == cc) dsum += acc[m][n][r];
        }
    dsum += __shfl_xor(dsum, 1);
    dsum += __shfl_xor(dsum, 2);
    dsum += __shfl_xor(dsum, 4);
    dsum += __shfl_xor(dsum, 8);
    dsum += __shfl_xor(dsum, 16);
    dsum += __shfl_xor(dsum, 32);
    if (lane == 0) atomicAdd(diagsum, dsum);
  }

#pragma unroll
  for (int m = 0; m < 4; ++m)
#pragma unroll
    for (int r = 0; r < 4; ++r) {
      float v = rowsum16_dpp(rowacc[m][r]);
      if (lm == 15)
        atomicAdd(&rowsum[brow * 128 + wm * 64 + m * 16 + lk * 4 + r], v);
    }
#pragma unroll
  for (int n = 0; n < 4; ++n) {
    float v = colacc[n];
    v += __shfl_xor(v, 16);
    v += __shfl_xor(v, 32);
    if (lk == 0)
      atomicAdd(&colsum[bcol * 128 + wn * 64 + n * 16 + lm], v);
  }
}

// ---------------- final reduction: parallel stats + tiny finisher ----------------
__global__ __launch_bounds__(256) void clip_stats(
    const float* __restrict__ rowsum, const float* __restrict__ colsum,
    float* __restrict__ partial) {
  __shared__ float sdata[4];
  const int i = blockIdx.x * 256 + threadIdx.x;
  float s = logf(rowsum[i]) + logf(colsum[i]);
  s += __shfl_xor(s, 1);
  s += __shfl_xor(s, 2);
  s += __shfl_xor(s, 4);
  s += __shfl_xor(s, 8);
  s += __shfl_xor(s, 16);
  s += __shfl_xor(s, 32);
  const int lane = threadIdx.x & 63, wv = threadIdx.x >> 6;
  if (lane == 0) sdata[wv] = s;
  __syncthreads();
  if (threadIdx.x == 0)
    atomicAdd(partial, sdata[0] + sdata[1] + sdata[2] + sdata[3]);
}

__global__ void clip_out(const float* __restrict__ partial,
                         const float* __restrict__ diagsum,
                         float* __restrict__ out) {
  if (threadIdx.x == 0)
    out[0] = (float)((double)SHIFT_C + (double)partial[0] * 0.5 / (double)NN
                     - (double)diagsum[0] / (double)NN);
}

extern "C" void kernel_launch(void* const* d_in, const int* in_sizes, int n_in,
                              void* d_out, int out_size, void* d_ws, size_t ws_size,
                              hipStream_t stream) {
  const float* X = (const float*)d_in[0];
  const float* Y = (const float*)d_in[1];

  const size_t bf16_bytes = (size_t)2 * NN * DD * sizeof(unsigned short);  // 16 MB
  const size_t stats_bytes = (size_t)(2 * NN + 2) * sizeof(float);

  if (ws_size >= bf16_bytes + stats_bytes) {
    unsigned short* Xb = (unsigned short*)d_ws;
    unsigned short* Yb = Xb + (size_t)NN * DD;
    float* rowsum = (float*)((unsigned char*)d_ws + bf16_bytes);
    float* colsum = rowsum + NN;
    float* diagsum = colsum + NN;
    float* partial = diagsum + 1;

    hipMemsetAsync(rowsum, 0, stats_bytes, stream);
    cvt_kernel<<<dim3(2 * NN * DD / 8 / 256), dim3(256), 0, stream>>>(X, Y, Xb, Yb);
    clip_gemm<<<dim3((NN / PANEL) * 8), dim3(THREADS), 0, stream>>>(
        Xb, Yb, rowsum, colsum, diagsum);
    clip_stats<<<dim3(NN / 256), dim3(256), 0, stream>>>(rowsum, colsum, partial);
    clip_out<<<dim3(1), dim3(64), 0, stream>>>(partial, diagsum, (float*)d_out);
  } else {
    float* rowsum = (float*)d_ws;
    float* colsum = rowsum + NN;
    float* diagsum = colsum + NN;
    float* partial = diagsum + 1;
    hipMemsetAsync(d_ws, 0, stats_bytes, stream);
    clip_main_fb<<<dim3((NN / 128) * (NN / 128)), dim3(256), 0, stream>>>(
        X, Y, rowsum, colsum, diagsum);
    clip_stats<<<dim3(NN / 256), dim3(256), 0, stream>>>(rowsum, colsum, partial);
    clip_out<<<dim3(1), dim3(64), 0, stream>>>(partial, diagsum, (float*)d_out);
  }
}

// Round 21
// 178.391 us; speedup vs baseline: 1.9879x; 1.2004x over previous
//
#include <hip/hip_runtime.h>
#include <hip/hip_bf16.h>

#define NN 16384
#define DD 256
#define PANEL 128              // A rows per block (resident in LDS, 64KB)
#define JCOLS 128              // cols per j-tile
#define BK 32                  // k per step
#define NT 8                   // K-steps per j (NT*BK == DD)
#define NJ 16                  // j-tiles per block (2048 cols)
#define THREADS 256            // 4 waves: 2m x 2n, wave = 64x64
#define A_BYTES (PANEL * DD * 2)   // 65536
#define B_BYTES (JCOLS * BK * 2)   // 8192
#define SHIFT_C 64.0f
#define LOG2E 1.4426950408889634f

typedef __attribute__((ext_vector_type(4))) float f32x4;
typedef __attribute__((ext_vector_type(8))) short bf16x8;

#if __has_builtin(__builtin_amdgcn_exp2f)
#define EXP2F(x) __builtin_amdgcn_exp2f(x)
#else
#define EXP2F(x) exp2f(x)
#endif

__device__ __forceinline__ unsigned pkbf(float a, float b) {
  float2 t; t.x = a; t.y = b;
  __hip_bfloat162 h = __float22bfloat162_rn(t);
  union { __hip_bfloat162 h; unsigned u; } cv;
  cv.h = h;
  return cv.u;
}

__device__ __forceinline__ float rowsum16_dpp(float v) {
  union { float f; int i; } x, t;
  x.f = v;
  t.i = __builtin_amdgcn_update_dpp(0, x.i, 0x111, 0xf, 0xf, true); x.f += t.f;
  t.i = __builtin_amdgcn_update_dpp(0, x.i, 0x112, 0xf, 0xf, true); x.f += t.f;
  t.i = __builtin_amdgcn_update_dpp(0, x.i, 0x114, 0xf, 0xf, true); x.f += t.f;
  t.i = __builtin_amdgcn_update_dpp(0, x.i, 0x118, 0xf, 0xf, true); x.f += t.f;
  return x.f;
}

// ---------------- pre-convert f32 -> bf16 ----------------
__global__ __launch_bounds__(256) void cvt_kernel(
    const float* __restrict__ X, const float* __restrict__ Y,
    unsigned short* __restrict__ Xb, unsigned short* __restrict__ Yb) {
  const int groups_per_arr = NN * DD / 8;
  int g = blockIdx.x * 256 + threadIdx.x;
  const float* src;
  unsigned short* dst;
  if (g < groups_per_arr) { src = X; dst = Xb; }
  else { src = Y; dst = Yb; g -= groups_per_arr; }
  float4 a = ((const float4*)src)[(size_t)g * 2];
  float4 b = ((const float4*)src)[(size_t)g * 2 + 1];
  uint4 p = { pkbf(a.x, a.y), pkbf(a.z, a.w), pkbf(b.x, b.y), pkbf(b.z, b.w) };
  ((uint4*)dst)[g] = p;
}

// ---------------- main fused GEMM + softmax-stats ----------------
// R16 structure (verified best: 194us, VGPR 88, no spill) with TWO deltas:
//  (1) setprio REMOVED (R20: −10%, lockstep regime — m190 reproduced)
//  (2) A-fragment register read-ahead: aP[2][4] ping-pong, prefetch
//      RDA(m,(t+1)&7) during step t's MFMAs (A panel is resident, so the
//      prefetch has no buffer hazard and crosses barriers in registers).
//      Post-barrier critical path: 8 LDS reads -> 4 (B only).
// Register cost +32 arch VGPRs (~120 total) — under the 128 clamp;
// WRITE_SIZE is the spill tripwire.
__global__ __launch_bounds__(THREADS, 2) void clip_gemm(
    const unsigned short* __restrict__ Xb, const unsigned short* __restrict__ Yb,
    float* __restrict__ rowsum, float* __restrict__ colsum,
    float* __restrict__ diagsum) {
  __shared__ __align__(16) unsigned char sm[A_BYTES + 2 * B_BYTES];  // 80KB

  const int tid = threadIdx.x;
  const int bid = blockIdx.x;
  // 1024 blocks = 8 colgroups (XCD-pinned: 1MB Y slice per XCD L2) x 128 panels
  const int colgroup = bid & 7;
  const int panel = bid >> 3;                 // 0..127
  const int rowbase = panel * PANEL;
  const int colbase = colgroup * (NJ * JCOLS);

  const unsigned short* xb = Xb + (size_t)rowbase * DD;
  const unsigned short* ybg = Yb + (size_t)colbase * DD;

  const int wid = tid >> 6, lane = tid & 63;
  const int wm = wid >> 1, wn = wid & 1;   // wave = rows [wm*64,+64) x cols [wn*64,+64)
  const int lm = lane & 15, lk = lane >> 4;

  // ---- A fill: 4096 slots of 16B ([128 rows][32 slots]); 16 per thread.
  // Physical slot s holds logical subslot g = s ^ (row&7) (involution).
#pragma unroll
  for (int p = 0; p < 16; ++p) {
    const int s = p * 256 + tid;
    const int row = s >> 5;
    const int g = (s & 31) ^ (row & 7);
    __builtin_amdgcn_global_load_lds(
        (const __attribute__((address_space(1))) unsigned*)(xb + row * DD + g * 8),
        (__attribute__((address_space(3))) unsigned*)(sm + s * 16), 16, 0, 0);
  }

  // ---- B staging offsets: 512 slots of 16B ([128 cols][4 slots]); 2/thread.
  // Physical slot holds logical subslot g = (s&3) ^ (col&3) (involution).
  int bsrc[2], bdst[2];
#pragma unroll
  for (int p = 0; p < 2; ++p) {
    const int s = p * 256 + tid;
    const int col = s >> 2;
    const int g = (s & 3) ^ (col & 3);
    bsrc[p] = col * DD + g * 8;                 // + jn*JCOLS*DD + tn*BK
    bdst[p] = A_BYTES + s * 16;                 // + buf*B_BYTES
  }

#define GLOADB(jn, tn, buf)                                                    \
  {                                                                            \
    _Pragma("unroll")                                                          \
    for (int p = 0; p < 2; ++p)                                                \
      __builtin_amdgcn_global_load_lds(                                        \
          (const __attribute__((address_space(1))) unsigned*)(ybg + (size_t)(jn) * (JCOLS * DD) + bsrc[p] + (tn) * BK), \
          (__attribute__((address_space(3))) unsigned*)(sm + (buf) * B_BYTES + bdst[p]), \
          16, 0, 0);                                                           \
  }

  // A read: row = wm*64 + m*16 + lm; physical slot = (t*4 + lk) ^ (lm&7)
#define RDA(m, t)                                                              \
  (*(const bf16x8*)(sm + (wm * 64 + (m) * 16 + lm) * (DD * 2) +                \
                    ((((t) * 4 + lk) ^ (lm & 7)) << 4)))
  // B read: col = wn*64 + nf*16 + lm; physical slot = lk ^ (lm&3)
#define RDB(nf, buf)                                                           \
  (*(const bf16x8*)(sm + A_BYTES + (buf) * B_BYTES +                           \
                    (wn * 64 + (nf) * 16 + lm) * (BK * 2) +                    \
                    ((lk ^ (lm & 3)) << 4)))

  f32x4 acc[4][4] = {};
  float rowacc[4][4];
#pragma unroll
  for (int m = 0; m < 4; ++m)
#pragma unroll
    for (int r = 0; r < 4; ++r) rowacc[m][r] = 0.f;
  float dsum = 0.f;
  const float negC = -(SHIFT_C * LOG2E);

  bf16x8 aP[2][4];  // A-frag ping-pong; parity static after NT unroll

  // prologue: stage B(j=0,t=0); drain A fill + stage(0); prefetch A(t=0)
  GLOADB(0, 0, 0);
  __syncthreads();
#pragma unroll
  for (int m = 0; m < 4; ++m) aP[0][m] = RDA(m, 0);

  for (int j = 0; j < NJ; ++j) {
#pragma unroll
    for (int t = 0; t < NT; ++t) {
      if (t > 0) { __syncthreads(); }
      else if (j > 0) { __syncthreads(); }
      // (j==0,t==0: prologue barrier already drained stage(0))
      // stage next step into the other buffer (one-step runway)
      if (t < NT - 1) { GLOADB(j, t + 1, (t + 1) & 1); }
      else if (j < NJ - 1) { GLOADB(j + 1, 0, 0); }   // (t+1)&1 == 0 at t=7
      const int buf = t & 1;
      bf16x8 b0[4];
#pragma unroll
      for (int nf = 0; nf < 4; ++nf) b0[nf] = RDB(nf, buf);
      // prefetch next step's A frags (resident panel, no hazard); these
      // overlap the MFMAs below and cross the next barrier in registers
#pragma unroll
      for (int m = 0; m < 4; ++m) aP[(t + 1) & 1][m] = RDA(m, (t + 1) & 7);
#pragma unroll
      for (int m = 0; m < 4; ++m) {
#pragma unroll
        for (int nf = 0; nf < 4; ++nf)
          acc[m][nf] = __builtin_amdgcn_mfma_f32_16x16x32_bf16(
              aP[t & 1][m], b0[nf], acc[m][nf], 0, 0, 0);
      }
    }

    // ---- per-j epilogue (runtime j-loop; overlaps next j's first stage) ----
    const int jc0 = colbase + j * JCOLS;
    float colacc[4] = {0.f, 0.f, 0.f, 0.f};
#pragma unroll
    for (int m = 0; m < 4; ++m)
#pragma unroll
      for (int nf = 0; nf < 4; ++nf)
#pragma unroll
        for (int r = 0; r < 4; ++r) {
          float e = EXP2F(__builtin_fmaf(acc[m][nf][r], LOG2E, negC));
          rowacc[m][r] += e;
          colacc[nf] += e;
        }
    if (jc0 == rowbase) {  // square 128-tiles: diagonal overlap iff equal
#pragma unroll
      for (int m = 0; m < 4; ++m)
#pragma unroll
        for (int nf = 0; nf < 4; ++nf)
#pragma unroll
          for (int r = 0; r < 4; ++r) {
            const int rr = wm * 64 + m * 16 + lk * 4 + r;
            const int cc = wn * 64 + nf * 16 + lm;
            if (rr == cc) dsum += acc[m][nf][r];
          }
    }
#pragma unroll
    for (int nf = 0; nf < 4; ++nf) {
      float v = colacc[nf];
      v += __shfl_xor(v, 16);
      v += __shfl_xor(v, 32);
      if (lk == 0)
        atomicAdd(&colsum[jc0 + wn * 64 + nf * 16 + lm], v);
    }
    const f32x4 z4 = {0.f, 0.f, 0.f, 0.f};
#pragma unroll
    for (int m = 0; m < 4; ++m)
#pragma unroll
      for (int nf = 0; nf < 4; ++nf) acc[m][nf] = z4;
  }
#undef GLOADB
#undef RDA
#undef RDB

  // ---- block-end: diagonal + row sums ----
  {
    float d = dsum;
    d += __shfl_xor(d, 1);
    d += __shfl_xor(d, 2);
    d += __shfl_xor(d, 4);
    d += __shfl_xor(d, 8);
    d += __shfl_xor(d, 16);
    d += __shfl_xor(d, 32);
    if (lane == 0 && d != 0.f) atomicAdd(diagsum, d);
  }
#pragma unroll
  for (int m = 0; m < 4; ++m)
#pragma unroll
    for (int r = 0; r < 4; ++r) {
      float v = rowsum16_dpp(rowacc[m][r]);
      if (lm == 15)
        atomicAdd(&rowsum[rowbase + wm * 64 + m * 16 + lk * 4 + r], v);
    }
}

// ---------------- fallback (reg-staging, no ws bf16 buffers) ----------------
__global__ __launch_bounds__(256) void clip_main_fb(
    const float* __restrict__ X, const float* __restrict__ Y,
    float* __restrict__ rowsum, float* __restrict__ colsum,
    float* __restrict__ diagsum) {
  __shared__ __align__(16) unsigned char smem[2 * 128 * 64 * 2];
  unsigned char* smA = smem;
  unsigned char* smB = smem + 128 * 64 * 2;

  const int tid = threadIdx.x;
  const int bid = blockIdx.x;
  const int swz = (bid & 7) * 2048 + (bid >> 3);
  const int brow = swz >> 7;
  const int bcol = swz & 127;

  const float* xb = X + (size_t)brow * 128 * DD;
  const float* yb = Y + (size_t)bcol * 128 * DD;

  const int wid = tid >> 6, lane = tid & 63;
  const int wm = wid >> 1, wn = wid & 1;
  const int lm = lane & 15, lk = lane >> 4;

  f32x4 acc[4][4] = {};

  for (int ks = 0; ks < 4; ++ks) {
    const int kbase = ks * 64;
    if (ks) __syncthreads();
#pragma unroll
    for (int i = 0; i < 4; ++i) {
      const int c = tid + i * 256;
      const int row = c >> 3, slot = c & 7;
      const int boff = row * 128 + ((slot << 4) ^ ((row & 7) << 4));
      const float* ga = xb + row * DD + kbase + (slot << 3);
      float4 a0 = *(const float4*)ga;
      float4 a1 = *(const float4*)(ga + 4);
      uint4 pa = { pkbf(a0.x, a0.y), pkbf(a0.z, a0.w),
                   pkbf(a1.x, a1.y), pkbf(a1.z, a1.w) };
      *(uint4*)(smA + boff) = pa;
      const float* gb = yb + row * DD + kbase + (slot << 3);
      float4 b0 = *(const float4*)gb;
      float4 b1 = *(const float4*)(gb + 4);
      uint4 pb = { pkbf(b0.x, b0.y), pkbf(b0.z, b0.w),
                   pkbf(b1.x, b1.y), pkbf(b1.w, b1.w) };
      pb.w = pkbf(b1.z, b1.w);
      pb = (uint4){ pkbf(b0.x, b0.y), pkbf(b0.z, b0.w),
                    pkbf(b1.x, b1.y), pkbf(b1.z, b1.w) };
      *(uint4*)(smB + boff) = pb;
    }
    __syncthreads();

#pragma unroll
    for (int kk = 0; kk < 2; ++kk) {
      const int kboff = kk * 64 + lk * 16;
      bf16x8 a[4], b[4];
#pragma unroll
      for (int m = 0; m < 4; ++m) {
        const int row = wm * 64 + m * 16 + lm;
        a[m] = *(const bf16x8*)(smA + row * 128 + (kboff ^ ((row & 7) << 4)));
      }
#pragma unroll
      for (int n = 0; n < 4; ++n) {
        const int row = wn * 64 + n * 16 + lm;
        b[n] = *(const bf16x8*)(smB + row * 128 + (kboff ^ ((row & 7) << 4)));
      }
#pragma unroll
      for (int m = 0; m < 4; ++m)
#pragma unroll
        for (int n = 0; n < 4; ++n)
          acc[m][n] = __builtin_amdgcn_mfma_f32_16x16x32_bf16(a[m], b[n], acc[m][n], 0, 0, 0);
    }
  }

  float rowacc[4][4];
  float colacc[4];
#pragma unroll
  for (int m = 0; m < 4; ++m)
#pragma unroll
    for (int r = 0; r < 4; ++r) rowacc[m][r] = 0.f;
#pragma unroll
  for (int n = 0; n < 4; ++n) colacc[n] = 0.f;

  const float negC = -(SHIFT_C * LOG2E);
#pragma unroll
  for (int m = 0; m < 4; ++m)
#pragma unroll
    for (int n = 0; n < 4; ++n)
#pragma unroll
      for (int r = 0; r < 4; ++r) {
        float e = EXP2F(__builtin_fmaf(acc[m][n][r], LOG2E, negC));
        rowacc[m][r] += e;
        colacc[n] += e;
      }

  if (brow == bcol && wm == wn) {
    float dsum = 0.f;
#pragma unroll
    for (int m = 0; m < 4; ++m)
#pragma unroll
      for (int n = 0; n < 4; ++n)
#pragma unroll
        for (int r = 0; r < 4; ++r) {
          const int rr = m * 16 + lk * 4 + r;
          const int cc = n * 16 + lm;
          if (rr == cc) dsum += acc[m][n][r];
        }
    dsum += __shfl_xor(dsum, 1);
    dsum += __shfl_xor(dsum, 2);
    dsum += __shfl_xor(dsum, 4);
    dsum += __shfl_xor(dsum, 8);
    dsum += __shfl_xor(dsum, 16);
    dsum += __shfl_xor(dsum, 32);
    if (lane == 0) atomicAdd(diagsum, dsum);
  }

#pragma unroll
  for (int m = 0; m < 4; ++m)
#pragma unroll
    for (int r = 0; r < 4; ++r) {
      float v = rowsum16_dpp(rowacc[m][r]);
      if (lm == 15)
        atomicAdd(&rowsum[brow * 128 + wm * 64 + m * 16 + lk * 4 + r], v);
    }
#pragma unroll
  for (int n = 0; n < 4; ++n) {
    float v = colacc[n];
    v += __shfl_xor(v, 16);
    v += __shfl_xor(v, 32);
    if (lk == 0)
      atomicAdd(&colsum[bcol * 128 + wn * 64 + n * 16 + lm], v);
  }
}

// ---------------- final reduction: parallel stats + tiny finisher ----------------
__global__ __launch_bounds__(256) void clip_stats(
    const float* __restrict__ rowsum, const float* __restrict__ colsum,
    float* __restrict__ partial) {
  __shared__ float sdata[4];
  const int i = blockIdx.x * 256 + threadIdx.x;
  float s = logf(rowsum[i]) + logf(colsum[i]);
  s += __shfl_xor(s, 1);
  s += __shfl_xor(s, 2);
  s += __shfl_xor(s, 4);
  s += __shfl_xor(s, 8);
  s += __shfl_xor(s, 16);
  s += __shfl_xor(s, 32);
  const int lane = threadIdx.x & 63, wv = threadIdx.x >> 6;
  if (lane == 0) sdata[wv] = s;
  __syncthreads();
  if (threadIdx.x == 0)
    atomicAdd(partial, sdata[0] + sdata[1] + sdata[2] + sdata[3]);
}

__global__ void clip_out(const float* __restrict__ partial,
                         const float* __restrict__ diagsum,
                         float* __restrict__ out) {
  if (threadIdx.x == 0)
    out[0] = (float)((double)SHIFT_C + (double)partial[0] * 0.5 / (double)NN
                     - (double)diagsum[0] / (double)NN);
}

extern "C" void kernel_launch(void* const* d_in, const int* in_sizes, int n_in,
                              void* d_out, int out_size, void* d_ws, size_t ws_size,
                              hipStream_t stream) {
  const float* X = (const float*)d_in[0];
  const float* Y = (const float*)d_in[1];

  const size_t bf16_bytes = (size_t)2 * NN * DD * sizeof(unsigned short);  // 16 MB
  const size_t stats_bytes = (size_t)(2 * NN + 2) * sizeof(float);

  if (ws_size >= bf16_bytes + stats_bytes) {
    unsigned short* Xb = (unsigned short*)d_ws;
    unsigned short* Yb = Xb + (size_t)NN * DD;
    float* rowsum = (float*)((unsigned char*)d_ws + bf16_bytes);
    float* colsum = rowsum + NN;
    float* diagsum = colsum + NN;
    float* partial = diagsum + 1;

    hipMemsetAsync(rowsum, 0, stats_bytes, stream);
    cvt_kernel<<<dim3(2 * NN * DD / 8 / 256), dim3(256), 0, stream>>>(X, Y, Xb, Yb);
    clip_gemm<<<dim3((NN / PANEL) * 8), dim3(THREADS), 0, stream>>>(
        Xb, Yb, rowsum, colsum, diagsum);
    clip_stats<<<dim3(NN / 256), dim3(256), 0, stream>>>(rowsum, colsum, partial);
    clip_out<<<dim3(1), dim3(64), 0, stream>>>(partial, diagsum, (float*)d_out);
  } else {
    float* rowsum = (float*)d_ws;
    float* colsum = rowsum + NN;
    float* diagsum = colsum + NN;
    float* partial = diagsum + 1;
    hipMemsetAsync(d_ws, 0, stats_bytes, stream);
    clip_main_fb<<<dim3((NN / 128) * (NN / 128)), dim3(256), 0, stream>>>(
        X, Y, rowsum, colsum, diagsum);
    clip_stats<<<dim3(NN / 256), dim3(256), 0, stream>>>(rowsum, colsum, partial);
    clip_out<<<dim3(1), dim3(64), 0, stream>>>(partial, diagsum, (float*)d_out);
  }
}